// Round 1
// baseline (827.846 us; speedup 1.0000x reference)
//
#include <hip/hip_runtime.h>

// ARIMA(p=2,d=1,q=2) epsilon extraction.
// B=1024 rows, L=65536. Output (B, 65535): eps[t] for t<65533, then 2 zeros.
// Recurrence per row: eps_t = c_t - th0*eps_{t-1} - th1*eps_{t-2}
//   c_t = y[3+t] - (1+phi0)*y[2+t] - phi1*y[1+t] - mu
// Parallelized by chunking time with a 64-step warmup (IIR decay makes the
// chunk-local state converge to the exact one far below the 0.15 threshold).

static constexpr int LROW = 65536;   // input row length
static constexpr int TOUT = 65535;   // output row length
static constexpr int TEPS = 65533;   // number of recurrence outputs
static constexpr int CK   = 256;     // outputs per thread (chunk)
static constexpr int WU   = 64;      // warmup steps
static constexpr int NCHUNK = 256;   // chunks per row (256*256 = 65536 >= 65533)

__global__ __launch_bounds__(256) void arima_eps_kernel(
    const float* __restrict__ y,
    const float* __restrict__ phi,
    const float* __restrict__ theta,
    const float* __restrict__ mu_p,
    float* __restrict__ out)
{
    const int g   = blockIdx.x * blockDim.x + threadIdx.x;
    const int row = g >> 8;        // 256 chunks per row
    const int k   = g & (NCHUNK - 1);

    const float phi0 = phi[0], phi1 = phi[1];
    const float th0  = theta[0], th1 = theta[1];
    const float mu   = mu_p[0];
    const float q2   = 1.0f + phi0;

    const float* __restrict__ yr   = y   + (size_t)row * LROW;
    float*       __restrict__ outr = out + (size_t)row * TOUT;

    const int t0 = k * CK;
    // float4 store covering t in [a-s, a+4-s) is 16B-aligned in flat space:
    // flat = row*65535 + t  =>  need t == row (mod 4)  =>  s = (-row) mod 4
    const int s = (4 - (row & 3)) & 3;

    float e1 = 0.f, e2 = 0.f;            // eps[t-1], eps[t-2]
    float p1 = 0.f, p2 = 0.f, p3 = 0.f;  // eps[a-3], eps[a-2], eps[a-1]

    int a = (k == 0) ? 0 : (t0 - WU);    // 4-aligned (t0 mult of 256, WU=64)
    float4 v0 = *(const float4*)(yr + a);   // y[a..a+3]

    // ---- warmup (no stores) ----
    for (; a < t0; a += 4) {
        float4 v1 = *(const float4*)(yr + a + 4);   // in-bounds: a+7 <= t0+3
        float c0 = v0.w - q2 * v0.z - phi1 * v0.y - mu;
        float c1 = v1.x - q2 * v0.w - phi1 * v0.z - mu;
        float c2 = v1.y - q2 * v1.x - phi1 * v0.w - mu;
        float c3 = v1.z - q2 * v1.y - phi1 * v1.x - mu;
        float f0 = c0 - th0 * e1 - th1 * e2;
        float f1 = c1 - th0 * f0 - th1 * e1;
        float f2 = c2 - th0 * f1 - th1 * f0;
        float f3 = c3 - th0 * f2 - th1 * f1;
        p1 = f1; p2 = f2; p3 = f3;
        e2 = f2; e1 = f3;
        v0 = v1;
    }

    const bool isTail = (k == NCHUNK - 1);

    // ---- output chunk ----
    for (; a < t0 + CK; a += 4) {
        int m1 = (a >> 2) + 1;
        if (m1 > LROW / 4 - 1) m1 = LROW / 4 - 1;   // clamp: garbage only feeds t>=65533 (discarded)
        float4 v1 = ((const float4*)yr)[m1];
        float c0 = v0.w - q2 * v0.z - phi1 * v0.y - mu;
        float c1 = v1.x - q2 * v0.w - phi1 * v0.z - mu;
        float c2 = v1.y - q2 * v1.x - phi1 * v0.w - mu;
        float c3 = v1.z - q2 * v1.y - phi1 * v1.x - mu;
        float f0 = c0 - th0 * e1 - th1 * e2;
        float f1 = c1 - th0 * f0 - th1 * e1;
        float f2 = c2 - th0 * f1 - th1 * f0;
        float f3 = c3 - th0 * f2 - th1 * f1;

        float sv[4];
        if      (s == 0) { sv[0] = f0; sv[1] = f1; sv[2] = f2; sv[3] = f3; }
        else if (s == 1) { sv[0] = p3; sv[1] = f0; sv[2] = f1; sv[3] = f2; }
        else if (s == 2) { sv[0] = p2; sv[1] = p3; sv[2] = f0; sv[3] = f1; }
        else             { sv[0] = p1; sv[1] = p2; sv[2] = p3; sv[3] = f0; }
        const int p = a - s;

        if (isTail) {
            // last chunk: scalar stores, clip to valid eps range; zeros later
            #pragma unroll
            for (int i = 0; i < 4; ++i) {
                int pp = p + i;
                if (pp <= TEPS - 1) outr[pp] = sv[i];
            }
        } else if (p >= 0) {
            *(float4*)(outr + p) = make_float4(sv[0], sv[1], sv[2], sv[3]);
        } else {
            // k==0, s>0, first group: head scalars (skip negative positions)
            #pragma unroll
            for (int i = 0; i < 4; ++i) {
                int pp = p + i;
                if (pp >= 0) outr[pp] = sv[i];
            }
        }

        p1 = f1; p2 = f2; p3 = f3;
        e2 = f2; e1 = f3;
        v0 = v1;
    }

    if (isTail) {
        outr[TEPS]     = 0.f;   // t = 65533
        outr[TEPS + 1] = 0.f;   // t = 65534
    }
}

extern "C" void kernel_launch(void* const* d_in, const int* in_sizes, int n_in,
                              void* d_out, int out_size, void* d_ws, size_t ws_size,
                              hipStream_t stream) {
    const float* y     = (const float*)d_in[0];
    const float* phi   = (const float*)d_in[1];
    const float* theta = (const float*)d_in[2];
    const float* mu    = (const float*)d_in[3];
    float* out = (float*)d_out;

    const int B = in_sizes[0] / LROW;           // 1024
    const int total_threads = B * NCHUNK;       // 262144
    dim3 block(256);
    dim3 grid(total_threads / 256);
    hipLaunchKernelGGL(arima_eps_kernel, grid, block, 0, stream,
                       y, phi, theta, mu, out);
}

// Round 2
// 454.536 us; speedup vs baseline: 1.8213x; 1.8213x over previous
//
#include <hip/hip_runtime.h>

// ARIMA(2,1,2) epsilon extraction via wave-parallel affine scan.
// Per row: eps_t = c_t - th0*eps_{t-1} - th1*eps_{t-2},
//   c_t = y[3+t] - (1+phi0)*y[2+t] - phi1*y[1+t] - mu,  t = 0..65532
// out[row][t] = eps_t (t<65533), 0 for t in {65533,65534}.
//
// Parallel structure: 1 wave per (row, chunk) with 16 chunks of 4096 outputs.
// Each wave processes its chunk in 17 groups of 256 steps (1st = warmup with
// zero init; IIR decay over 256 steps makes chunk-local state exact to <1e-30).
// Within a group: lane k owns steps 4k..4k+3 -> loads are one aligned float4
// per lane = contiguous 1KB per wave (perfectly coalesced). The recurrence is
// solved with a Hillis-Steele scan over affine maps; since every lane's local
// matrix is A^4 (constant), only the 2-vector part needs scanning, using
// precomputed A^(4*2^j) matrices. Stores are contiguous 1KB/wave, 16B-aligned
// via the per-row shift s = (-row) mod 4 (row stride 65535 is odd).

static constexpr int LROW = 65536;
static constexpr int TOUT = 65535;
static constexpr int TEPS = 65533;
static constexpr int NCH  = 16;              // chunks per row
static constexpr int CHUNK = LROW / NCH;     // 4096
static constexpr int NG = CHUNK / 256;       // 16 output groups per chunk

__global__ __launch_bounds__(256) void arima_scan_kernel(
    const float* __restrict__ y,
    const float* __restrict__ phi,
    const float* __restrict__ theta,
    const float* __restrict__ mu_p,
    float* __restrict__ out)
{
    const int gtid = blockIdx.x * blockDim.x + threadIdx.x;
    const int wave = gtid >> 6;
    const int lane = gtid & 63;
    const int row  = wave >> 4;              // 16 chunks per row
    const int ch   = wave & (NCH - 1);

    const float phi0 = phi[0], phi1 = phi[1];
    const float th0  = theta[0], th1 = theta[1];
    const float mu   = mu_p[0];
    const float q2   = 1.0f + phi0;

    // a_n: a_0=1, a_1=-th0, a_n = -th0*a_{n-1} - th1*a_{n-2}.  A^n =
    // [[a_n, -th1*a_{n-1}],[a_{n-1}, -th1*a_{n-2}]].  Need n = 4*2^j, j=0..5.
    float mjA[6], mjB[6], mjC[6], mjD[6];
    {
        float am1 = 1.0f, am2 = 0.0f;        // a_0, a_{-1}
        int idx = 0, next = 4;
        for (int n = 1; n <= 128; ++n) {
            float an = -th0 * am1 - th1 * am2;
            if (n == next) {
                mjA[idx] = an;
                mjB[idx] = -th1 * am1;
                mjC[idx] = am1;
                mjD[idx] = -th1 * am2;
                idx++; next <<= 1;
            }
            am2 = am1; am1 = an;
        }
    }
    const float a1 = -th0;
    const float a2 = -th0 * a1 - th1;
    const float a3 = -th0 * a2 - th1 * a1;

    const float* __restrict__ yr   = y   + (size_t)row * LROW;
    float*       __restrict__ outr = out + (size_t)row * TOUT;
    const int s = (4 - (row & 3)) & 3;       // store shift (wave-uniform)

    const int t0 = ch * CHUNK;
    const bool firstCh = (ch == 0);
    const bool lastCh  = (ch == NCH - 1);

    float E1 = 0.f, E2 = 0.f;                // carry: eps at group-start -1,-2
    float C1p = 0.f, C2p = 0.f, C3p = 0.f;   // prev group lane63 f1,f2,f3

    const int g0 = firstCh ? 1 : 0;          // chunk 0: no warmup group
    for (int g = g0; g <= NG; ++g) {
        const int baseg = t0 + (g - 1) * 256;   // g=0 -> warmup at t0-256
        const int base  = baseg + 4 * lane;

        int qv = base >> 2;
        int qw = qv + 1; if (qw > LROW / 4 - 1) qw = LROW / 4 - 1; // tail clamp
        float4 v = ((const float4*)yr)[qv];
        float4 w = ((const float4*)yr)[qw];

        float c0 = v.w - q2 * v.z - phi1 * v.y - mu;
        float c1 = w.x - q2 * v.w - phi1 * v.z - mu;
        float c2 = w.y - q2 * w.x - phi1 * v.w - mu;
        float c3 = w.z - q2 * w.y - phi1 * w.x - mu;

        // local affine offset over 4 steps from zero state: [eps3, eps2]
        float vh = fmaf(a3, c0, fmaf(a2, c1, fmaf(a1, c2, c3)));
        float vl = fmaf(a2, c0, fmaf(a1, c1, c2));

        // fold group-carry state into lane 0:  v0 <- A^4*[E1,E2] + v0
        if (lane == 0) {
            vh = fmaf(mjA[0], E1, fmaf(mjB[0], E2, vh));
            vl = fmaf(mjC[0], E1, fmaf(mjD[0], E2, vl));
        }

        // Hillis-Steele scan of the vector parts (matrix part is uniform)
        #pragma unroll
        for (int j = 0; j < 6; ++j) {
            const int d = 1 << j;
            float ph = __shfl_up(vh, d);
            float pl = __shfl_up(vl, d);
            if (lane >= d) {
                vh = fmaf(mjA[j], ph, fmaf(mjB[j], pl, vh));
                vl = fmaf(mjC[j], ph, fmaf(mjD[j], pl, vl));
            }
        }

        // entering state for this lane = previous lane's scanned state
        float eh = __shfl_up(vh, 1);
        float el = __shfl_up(vl, 1);
        float e1 = (lane == 0) ? E1 : eh;
        float e2 = (lane == 0) ? E2 : el;

        float f0 = fmaf(-th0, e1, fmaf(-th1, e2, c0));
        float f1 = fmaf(-th0, f0, fmaf(-th1, e1, c1));
        float f2 = fmaf(-th0, f1, fmaf(-th1, f0, c2));
        float f3 = fmaf(-th0, f2, fmaf(-th1, f1, c3));

        // next-group carries (lane 63's last values)
        float nE1 = __shfl(f3, 63);
        float nE2 = __shfl(f2, 63);
        float nC1 = __shfl(f1, 63);

        if (g >= 1) {
            float sv0, sv1, sv2, sv3;
            if (s == 0) { sv0 = f0; sv1 = f1; sv2 = f2; sv3 = f3; }
            else {
                float pf1 = __shfl_up(f1, 1); if (lane == 0) pf1 = C1p;
                float pf2 = __shfl_up(f2, 1); if (lane == 0) pf2 = C2p;
                float pf3 = __shfl_up(f3, 1); if (lane == 0) pf3 = C3p;
                if (s == 1)      { sv0 = pf3; sv1 = f0;  sv2 = f1;  sv3 = f2; }
                else if (s == 2) { sv0 = pf2; sv1 = pf3; sv2 = f0;  sv3 = f1; }
                else             { sv0 = pf1; sv1 = pf2; sv2 = pf3; sv3 = f0; }
            }
            const int p = base - s;          // first stored t
            const bool headSp = (firstCh && g == 1 && s > 0);
            const bool tailSp = (lastCh && g == NG);
            if (!headSp && !tailSp) {
                *(float4*)(outr + p) = make_float4(sv0, sv1, sv2, sv3);
            } else {
                float svv[4] = {sv0, sv1, sv2, sv3};
                #pragma unroll
                for (int i = 0; i < 4; ++i) {
                    int t = p + i;
                    if (t >= 0 && t < TOUT) outr[t] = (t < TEPS) ? svv[i] : 0.f;
                }
            }
        }
        E1 = nE1; E2 = nE2;
        C3p = nE1; C2p = nE2; C1p = nC1;
    }

    // positions {65533, 65534} may be missed by the shifted quad path; they
    // are zeros by definition — write them unconditionally from lane 0.
    if (lastCh && lane == 0) { outr[TEPS] = 0.f; outr[TEPS + 1] = 0.f; }
}

extern "C" void kernel_launch(void* const* d_in, const int* in_sizes, int n_in,
                              void* d_out, int out_size, void* d_ws, size_t ws_size,
                              hipStream_t stream) {
    const float* y     = (const float*)d_in[0];
    const float* phi   = (const float*)d_in[1];
    const float* theta = (const float*)d_in[2];
    const float* mu    = (const float*)d_in[3];
    float* out = (float*)d_out;

    const int B = in_sizes[0] / LROW;        // 1024
    const int total_threads = B * NCH * 64;  // 1 wave per (row, chunk)
    dim3 block(256);
    dim3 grid(total_threads / 256);
    hipLaunchKernelGGL(arima_scan_kernel, grid, block, 0, stream,
                       y, phi, theta, mu, out);
}